// Round 5
// baseline (528.918 us; speedup 1.0000x reference)
//
#include <hip/hip_runtime.h>
#include <stdint.h>
#include <stddef.h>

#define TOK    16384     // B*S
#define DDIM   1024
#define NEXP   8
#define CAPB   20        // 128-row blocks per expert (capacity 2560 >= 2048+11sigma)
#define CAP    (CAPB * 128)
#define NSLOT  (NEXP * CAP)
#define MARGIN 2e-4f     // split-logit ambiguity margin (~40 sigma of split err)
#define AMBIG_CAP 1024
#define NINF  (-3.0e38f)

typedef __bf16 bf16x8 __attribute__((ext_vector_type(8)));
typedef float  f32x4  __attribute__((ext_vector_type(4)));
typedef unsigned short u16x8 __attribute__((ext_vector_type(8)));

__device__ __forceinline__ unsigned short f2bf(float f) {
    unsigned int u = __float_as_uint(f);
    u += 0x7fff + ((u >> 16) & 1);          // round-to-nearest-even
    return (unsigned short)(u >> 16);
}
__device__ __forceinline__ float bf2f(unsigned short h) {
    return __uint_as_float((unsigned int)h << 16);
}

__device__ __forceinline__ void gload_lds16(const void* g, void* l) {
    __builtin_amdgcn_global_load_lds(
        (const __attribute__((address_space(1))) unsigned int*)g,
        (__attribute__((address_space(3))) unsigned int*)l, 16, 0, 0);
}

// ---------------------------------------------------------------------------
// Weight prep, 64x64 tiles (256B-wide reads, 128B-wide writes):
// z<8: We[e][k][n] -> WeT[e][n][k] bf16; z==8: Wg -> WgT hi/lo bf16 split.
// ---------------------------------------------------------------------------
__global__ __launch_bounds__(256) void prep_weights(
    const float* __restrict__ We, const float* __restrict__ Wg,
    unsigned short* __restrict__ WeT,
    unsigned short* __restrict__ Wh, unsigned short* __restrict__ Wl)
{
    __shared__ float tile[64][65];
    const int z  = blockIdx.z;
    const int k0 = blockIdx.x * 64;
    const int n0 = blockIdx.y * 64;
    const int tid = threadIdx.x;
    const float* src = (z < NEXP) ? We + (size_t)z * DDIM * DDIM : Wg;
#pragma unroll
    for (int pass = 0; pass < 4; pass++) {
        const int r = pass * 16 + (tid >> 4);
        const int c = (tid & 15) * 4;
        *(float4*)&tile[r][c] = *(const float4*)&src[(size_t)(k0 + r) * DDIM + n0 + c];
    }
    __syncthreads();
#pragma unroll
    for (int pass = 0; pass < 4; pass++) {
        const int n  = pass * 16 + (tid >> 4);
        const int kq = (tid & 15) * 4;
        const size_t o = (size_t)(n0 + n) * DDIM + k0 + kq;
        float v0 = tile[kq + 0][n], v1 = tile[kq + 1][n];
        float v2 = tile[kq + 2][n], v3 = tile[kq + 3][n];
        if (z < NEXP) {
            ushort4 hv;
            hv.x = f2bf(v0); hv.y = f2bf(v1); hv.z = f2bf(v2); hv.w = f2bf(v3);
            *(ushort4*)&WeT[(size_t)z * DDIM * DDIM + o] = hv;
        } else {
            ushort4 hv, lv;
            hv.x = f2bf(v0); lv.x = f2bf(v0 - bf2f(hv.x));
            hv.y = f2bf(v1); lv.y = f2bf(v1 - bf2f(hv.y));
            hv.z = f2bf(v2); lv.z = f2bf(v2 - bf2f(hv.z));
            hv.w = f2bf(v3); lv.w = f2bf(v3 - bf2f(hv.w));
            *(ushort4*)&Wh[o] = hv;
            *(ushort4*)&Wl[o] = lv;
        }
    }
}

// ---------------------------------------------------------------------------
// Gating GEMM (3-term bf16 split MFMA), A split from fp32 x in-reg (R2-proven
// ~free), B hi/lo via global_load_lds. Fused per-tile row-stats AND, in the
// last-arriving block per row-tile (done[rb] atomic, device-scope fences),
// the cross-nb combine + softmax p + expert slot assignment.
// ---------------------------------------------------------------------------
__global__ __launch_bounds__(256) void gating_mfma(
    const float* __restrict__ x,
    const unsigned short* __restrict__ WgTh, const unsigned short* __restrict__ WgTl,
    const float* __restrict__ bg, float4* __restrict__ partials,
    float* __restrict__ p, int* __restrict__ cursor, int* __restrict__ done,
    int* __restrict__ row_of_slot, int* __restrict__ slot_of,
    int* __restrict__ ambig, int* __restrict__ n_ambig)
{
    __shared__ unsigned short Ah[128 * 32], Al[128 * 32];
    __shared__ unsigned short Bh[128 * 32], Bl[128 * 32];
    __shared__ float4 stat[128][2];
    const int rb = blockIdx.x;
    const int nb = blockIdx.y;
    const int tid  = threadIdx.x;
    const int lane = tid & 63;
    const int wave = tid >> 6;
    const int q    = lane >> 4;
    const int m16  = lane & 15;
    const int wrow = (wave & 1) * 64;
    const int wcol = (wave >> 1) * 64;
    const int half = wave >> 1;
    const int xq   = (q ^ (m16 & 3)) * 8;

    const float* Ag = x + (size_t)rb * 128 * DDIM;
    const unsigned short* Bhg = WgTh + (size_t)nb * 128 * DDIM;
    const unsigned short* Blg = WgTl + (size_t)nb * 128 * DDIM;

    f32x4 acc[4][4];
#pragma unroll
    for (int i = 0; i < 4; i++)
#pragma unroll
        for (int j = 0; j < 4; j++) acc[i][j] = (f32x4){0.f, 0.f, 0.f, 0.f};

    for (int k0 = 0; k0 < DDIM; k0 += 32) {
#pragma unroll
        for (int i = 0; i < 2; i++) {
            const int idx = tid + i * 256;
            const int r = idx >> 2;
            const int kk = ((idx & 3) ^ (r & 3)) * 8;
            const size_t go = (size_t)r * DDIM + k0 + kk;
            gload_lds16(Bhg + go, &Bh[idx * 8]);
            gload_lds16(Blg + go, &Bl[idx * 8]);
            float4 v0 = *(const float4*)(Ag + go);
            float4 v1 = *(const float4*)(Ag + go + 4);
            float vv[8] = {v0.x, v0.y, v0.z, v0.w, v1.x, v1.y, v1.z, v1.w};
            u16x8 hh, ll;
#pragma unroll
            for (int j = 0; j < 8; j++) {
                unsigned short h = f2bf(vv[j]);
                hh[j] = h;
                ll[j] = f2bf(vv[j] - bf2f(h));
            }
            *(u16x8*)&Ah[idx * 8] = hh;
            *(u16x8*)&Al[idx * 8] = ll;
        }
        __syncthreads();
        bf16x8 ah[4], al[4], bhf[4], blf[4];
#pragma unroll
        for (int i = 0; i < 4; i++) {
            ah[i] = *(const bf16x8*)&Ah[(wrow + i * 16 + m16) * 32 + xq];
            al[i] = *(const bf16x8*)&Al[(wrow + i * 16 + m16) * 32 + xq];
        }
#pragma unroll
        for (int j = 0; j < 4; j++) {
            bhf[j] = *(const bf16x8*)&Bh[(wcol + j * 16 + m16) * 32 + xq];
            blf[j] = *(const bf16x8*)&Bl[(wcol + j * 16 + m16) * 32 + xq];
        }
#pragma unroll
        for (int i = 0; i < 4; i++)
#pragma unroll
            for (int j = 0; j < 4; j++) {
                acc[i][j] = __builtin_amdgcn_mfma_f32_16x16x32_bf16(ah[i], bhf[j], acc[i][j], 0, 0, 0);
                acc[i][j] = __builtin_amdgcn_mfma_f32_16x16x32_bf16(ah[i], blf[j], acc[i][j], 0, 0, 0);
                acc[i][j] = __builtin_amdgcn_mfma_f32_16x16x32_bf16(al[i], bhf[j], acc[i][j], 0, 0, 0);
            }
        __syncthreads();
    }

    // ---- fused row stats over this 128x128 tile ----
    float bgv[4];
#pragma unroll
    for (int j = 0; j < 4; j++) bgv[j] = bg[nb * 128 + wcol + j * 16 + m16];

#pragma unroll
    for (int i = 0; i < 4; i++) {
#pragma unroll
        for (int r = 0; r < 4; r++) {
            const int rloc = wrow + i * 16 + q * 4 + r;
            float v[4];
#pragma unroll
            for (int j = 0; j < 4; j++) v[j] = acc[i][j][r] + bgv[j];
            float t1 = v[0], t2 = NINF;
            int c1 = nb * 128 + wcol + m16;
#pragma unroll
            for (int j = 1; j < 4; j++) {
                const int cj = nb * 128 + wcol + j * 16 + m16;
                if (v[j] > t1) { t2 = t1; t1 = v[j]; c1 = cj; }
                else t2 = fmaxf(t2, v[j]);
            }
#pragma unroll
            for (int mask = 1; mask <= 8; mask <<= 1) {
                float o1 = __shfl_xor(t1, mask, 64);
                int   oc = __shfl_xor(c1, mask, 64);
                float o2 = __shfl_xor(t2, mask, 64);
                if (o1 > t1 || (o1 == t1 && oc < c1)) {
                    t2 = fmaxf(t1, o2); t1 = o1; c1 = oc;
                } else {
                    t2 = fmaxf(t2, o1);
                }
            }
            float s = expf(v[0] - t1) + expf(v[1] - t1) +
                      expf(v[2] - t1) + expf(v[3] - t1);
#pragma unroll
            for (int mask = 1; mask <= 8; mask <<= 1)
                s += __shfl_xor(s, mask, 64);
            if (m16 == 0) {
                float4 st; st.x = t1; st.y = t2; st.z = s; st.w = __int_as_float(c1);
                stat[rloc][half] = st;
            }
        }
    }
    __syncthreads();
    if (tid < 128) {
        float4 h0 = stat[tid][0], h1 = stat[tid][1];
        float T1 = h0.x, T2 = h0.y, S;
        int C = __float_as_int(h0.w);
        if (h1.x > T1) {
            T2 = fmaxf(T1, h1.y);
            S = h0.z * expf(T1 - h1.x) + h1.z;
            T1 = h1.x; C = __float_as_int(h1.w);
        } else {
            T2 = fmaxf(T2, h1.x);
            S = h0.z + h1.z * expf(h1.x - T1);
        }
        float4 o; o.x = T1; o.y = T2; o.z = S; o.w = __int_as_float(C);
        partials[(size_t)nb * TOK + rb * 128 + tid] = o;
    }
    __syncthreads();

    // ---- last-arriving block for this rb does the cross-nb combine ----
    __shared__ int sdone;
    if (tid == 0) {
        __threadfence();                        // release partials (device scope)
        sdone = atomicAdd(&done[rb], 1);
    }
    __syncthreads();
    if (sdone != NEXP - 1) return;
    __threadfence();                            // acquire other blocks' partials

    __shared__ int hh_[NEXP], base_[NEXP], lh_[NEXP];
    if (tid < NEXP) { hh_[tid] = 0; lh_[tid] = 0; }
    __syncthreads();
    int my_e = 0, my_row = 0; bool my_amb = false;
    if (tid < 128) {
        my_row = rb * 128 + tid;
        float4 t0 = partials[my_row];
        float T1 = t0.x, T2 = t0.y, S = t0.z;
        int C = __float_as_int(t0.w);
#pragma unroll
        for (int nbb = 1; nbb < NEXP; nbb++) {
            float4 u = partials[(size_t)nbb * TOK + my_row];
            if (u.x > T1) {
                T2 = fmaxf(T1, u.y);
                S = S * expf(T1 - u.x) + u.z;
                T1 = u.x; C = __float_as_int(u.w);
            } else {
                T2 = fmaxf(T2, u.x);
                S += u.z * expf(u.x - T1);
            }
        }
        p[my_row] = 1.0f / S;
        my_e = C & (NEXP - 1);
        my_amb = (T1 - T2 < MARGIN);
        if (my_amb) {
            int k = atomicAdd(n_ambig, 1);
            if (k < AMBIG_CAP) ambig[k] = my_row;
        } else {
            atomicAdd(&hh_[my_e], 1);
        }
    }
    __syncthreads();
    if (tid < NEXP && hh_[tid] > 0) base_[tid] = atomicAdd(&cursor[tid], hh_[tid]);
    __syncthreads();
    if (tid < 128) {
        if (!my_amb) {
            int rr = atomicAdd(&lh_[my_e], 1);
            int slot = my_e * CAP + base_[my_e] + rr;
            row_of_slot[slot] = my_row;
            slot_of[my_row] = slot;
        } else {
            slot_of[my_row] = -1;               // fixup fills in
        }
    }
}

// ---------------------------------------------------------------------------
// Fix-up: ambiguous rows recomputed whole-row in fp64 (coalesced k-major
// Wg reads), exact argmax (numpy first-occurrence) + exact p + slot assign.
// ---------------------------------------------------------------------------
__global__ __launch_bounds__(256) void fixup(
    const float* __restrict__ x, const float* __restrict__ Wg,
    const float* __restrict__ bg, const int* __restrict__ ambig,
    const int* __restrict__ n_ambig, int* __restrict__ cursor,
    int* __restrict__ row_of_slot, int* __restrict__ slot_of,
    float* __restrict__ pout)
{
    int n = *n_ambig; if (n > AMBIG_CAP) n = AMBIG_CAP;
    const int tid = threadIdx.x;
    __shared__ float xsh[DDIM];
    __shared__ double sv[256];
    __shared__ int    si[256];
    for (int ii = blockIdx.x; ii < n; ii += 64) {
        const int row = ambig[ii];
        for (int k = tid; k < DDIM; k += 256) xsh[k] = x[(size_t)row * DDIM + k];
        __syncthreads();
        double a0 = 0, a1 = 0, a2 = 0, a3 = 0;
        for (int k = 0; k < DDIM; k++) {
            const double xv = (double)xsh[k];
            const float* wr = Wg + (size_t)k * DDIM;
            a0 += xv * (double)wr[tid];
            a1 += xv * (double)wr[tid + 256];
            a2 += xv * (double)wr[tid + 512];
            a3 += xv * (double)wr[tid + 768];
        }
        a0 += (double)bg[tid];       a1 += (double)bg[tid + 256];
        a2 += (double)bg[tid + 512]; a3 += (double)bg[tid + 768];
        double m = a0; int mc = tid;
        if (a1 > m) { m = a1; mc = tid + 256; }
        if (a2 > m) { m = a2; mc = tid + 512; }
        if (a3 > m) { m = a3; mc = tid + 768; }
        sv[tid] = m; si[tid] = mc;
        __syncthreads();
        for (int off = 128; off > 0; off >>= 1) {
            if (tid < off) {
                double ov = sv[tid + off]; int oi = si[tid + off];
                if (ov > sv[tid] || (ov == sv[tid] && oi < si[tid])) {
                    sv[tid] = ov; si[tid] = oi;
                }
            }
            __syncthreads();
        }
        const double M = sv[0];
        const int best = si[0];
        __syncthreads();
        double s = exp(a0 - M) + exp(a1 - M) + exp(a2 - M) + exp(a3 - M);
        sv[tid] = s;
        __syncthreads();
        for (int off = 128; off > 0; off >>= 1) {
            if (tid < off) sv[tid] += sv[tid + off];
            __syncthreads();
        }
        if (tid == 0) {
            const int e = best & (NEXP - 1);
            pout[row] = (float)(1.0 / sv[0]);
            int slot = e * CAP + atomicAdd(&cursor[e], 1);
            row_of_slot[slot] = row;
            slot_of[row] = slot;
        }
        __syncthreads();
    }
}

// ---------------------------------------------------------------------------
// Gather fp32 x rows -> bf16 expert-sorted buffer (coalesced both sides)
// ---------------------------------------------------------------------------
__global__ __launch_bounds__(256) void gather_sorted(
    const float* __restrict__ x, const int* __restrict__ slot_of,
    unsigned short* __restrict__ xs)
{
    const int t = blockIdx.x;
    const int slot = slot_of[t];
    if ((unsigned)slot >= NSLOT) return;        // robustness vs ambig overflow
    const int c = threadIdx.x * 4;
    float4 v = *(const float4*)&x[(size_t)t * DDIM + c];
    ushort4 o;
    o.x = f2bf(v.x); o.y = f2bf(v.y); o.z = f2bf(v.z); o.w = f2bf(v.w);
    *(ushort4*)&xs[(size_t)slot * DDIM + c] = o;
}

// ---------------------------------------------------------------------------
// Expert GEMM, m97 shape: coalesced global_load_lds for A (sorted xs) and B
// (WeT). Validity from cursor[e] (no row_of_slot memset needed).
// Epilogue: relu(acc+be)*p scattered to token rows. e = rb / CAPB.
// ---------------------------------------------------------------------------
__global__ __launch_bounds__(256) void expert_gemm(
    const unsigned short* __restrict__ xs, const unsigned short* __restrict__ WeT,
    const float* __restrict__ be, const float* __restrict__ p,
    const int* __restrict__ row_of_slot, const int* __restrict__ cursor,
    float* __restrict__ out)
{
    __shared__ unsigned short Asm[128 * 32];
    __shared__ unsigned short Bsm[128 * 32];
    __shared__ int rs[128];
    const int rb = blockIdx.x;
    const int nb = blockIdx.y;
    const int e  = rb / CAPB;
    const int rloc = (rb - e * CAPB) * 128;
    const int cnt = cursor[e];
    if (rloc >= cnt) return;                    // wholly-empty capacity block
    const int nvalid = min(128, cnt - rloc);
    const int tid  = threadIdx.x;

    if (tid < 128) rs[tid] = (tid < nvalid) ? row_of_slot[rb * 128 + tid] : -1;
    __syncthreads();

    const int lane = tid & 63;
    const int wave = tid >> 6;
    const int q    = lane >> 4;
    const int m16  = lane & 15;
    const int wrow = (wave & 1) * 64;
    const int wcol = (wave >> 1) * 64;
    const int xq   = (q ^ (m16 & 3)) * 8;

    const unsigned short* Aglob = xs + (size_t)rb * 128 * DDIM;
    const unsigned short* Bglob = WeT + (size_t)e * DDIM * DDIM + (size_t)nb * 128 * DDIM;

    f32x4 acc[4][4];
#pragma unroll
    for (int i = 0; i < 4; i++)
#pragma unroll
        for (int j = 0; j < 4; j++) acc[i][j] = (f32x4){0.f, 0.f, 0.f, 0.f};

    for (int k0 = 0; k0 < DDIM; k0 += 32) {
#pragma unroll
        for (int i = 0; i < 2; i++) {
            const int idx = tid + i * 256;
            const int r = idx >> 2;
            const int kk = ((idx & 3) ^ (r & 3)) * 8;
            const size_t go = (size_t)r * DDIM + k0 + kk;
            gload_lds16(Aglob + go, &Asm[idx * 8]);
            gload_lds16(Bglob + go, &Bsm[idx * 8]);
        }
        __syncthreads();
        bf16x8 af[4], bfr[4];
#pragma unroll
        for (int i = 0; i < 4; i++)
            af[i] = *(const bf16x8*)&Asm[(wrow + i * 16 + m16) * 32 + xq];
#pragma unroll
        for (int j = 0; j < 4; j++)
            bfr[j] = *(const bf16x8*)&Bsm[(wcol + j * 16 + m16) * 32 + xq];
#pragma unroll
        for (int i = 0; i < 4; i++)
#pragma unroll
            for (int j = 0; j < 4; j++)
                acc[i][j] = __builtin_amdgcn_mfma_f32_16x16x32_bf16(
                    af[i], bfr[j], acc[i][j], 0, 0, 0);
        __syncthreads();
    }

    float bev[4];
#pragma unroll
    for (int j = 0; j < 4; j++) bev[j] = be[e * DDIM + nb * 128 + wcol + j * 16 + m16];
#pragma unroll
    for (int i = 0; i < 4; i++)
#pragma unroll
        for (int r = 0; r < 4; r++) {
            const int t = rs[wrow + i * 16 + q * 4 + r];
            if (t < 0) continue;
            const float pv = p[t];
#pragma unroll
            for (int j = 0; j < 4; j++) {
                const int n = nb * 128 + wcol + j * 16 + m16;
                float v = acc[i][j][r] + bev[j];
                v = v > 0.f ? v : 0.f;
                out[(size_t)t * DDIM + n] = v * pv;
            }
        }
}

// ---------------------------------------------------------------------------
extern "C" void kernel_launch(void* const* d_in, const int* in_sizes, int n_in,
                              void* d_out, int out_size, void* d_ws, size_t ws_size,
                              hipStream_t stream)
{
    const float* x  = (const float*)d_in[0];
    const float* Wg = (const float*)d_in[1];
    const float* bg = (const float*)d_in[2];
    const float* We = (const float*)d_in[3];
    const float* be = (const float*)d_in[4];
    float* out = (float*)d_out;

    char* ws = (char*)d_ws;
    // control block (zeroed in ONE memset): cursor[8], n_ambig[1], done[128]
    int* cursor = (int*)ws;
    int* n_ambig = cursor + NEXP;
    int* done = n_ambig + 1;
    ws += (NEXP + 1 + 128) * 4;
    int* ambig = (int*)ws;                      ws += AMBIG_CAP * 4;
    unsigned short* WeT = (unsigned short*)ws;  ws += (size_t)NEXP * DDIM * DDIM * 2;
    unsigned short* WgTh = (unsigned short*)ws; ws += (size_t)DDIM * DDIM * 2;
    unsigned short* WgTl = (unsigned short*)ws; ws += (size_t)DDIM * DDIM * 2;
    float4* partials = (float4*)ws;             ws += (size_t)NEXP * TOK * 16;
    float* p = (float*)ws;                      ws += (size_t)TOK * 4;
    int* slot_of = (int*)ws;                    ws += (size_t)TOK * 4;
    int* row_of_slot = (int*)ws;                ws += (size_t)NSLOT * 4;
    unsigned short* xs = (unsigned short*)ws;   ws += (size_t)NSLOT * DDIM * 2;

    hipMemsetAsync(cursor, 0, (NEXP + 1 + 128) * 4, stream);

    prep_weights<<<dim3(16, 16, NEXP + 1), 256, 0, stream>>>(We, Wg, WeT, WgTh, WgTl);
    gating_mfma<<<dim3(TOK / 128, DDIM / 128), 256, 0, stream>>>(
        x, WgTh, WgTl, bg, partials, p, cursor, done,
        row_of_slot, slot_of, ambig, n_ambig);
    fixup<<<64, 256, 0, stream>>>(x, Wg, bg, ambig, n_ambig, cursor,
                                  row_of_slot, slot_of, p);
    gather_sorted<<<TOK, 256, 0, stream>>>(x, slot_of, xs);
    expert_gemm<<<dim3(CAPB * NEXP, DDIM / 128), 256, 0, stream>>>(
        xs, WeT, be, p, row_of_slot, cursor, out);
}